// Round 18
// baseline (369.451 us; speedup 1.0000x reference)
//
#include <hip/hip_runtime.h>
#include <hip/hip_fp16.h>

#define TLEN 8192
#define NTS  256
#define CLEN 32
#define NCH  256           // TLEN / CLEN
#define SLOT2 66048        // 256*128 bf16 (65536) + 128 f32 scales (512)
#define QSTR 272           // qt8 row stride (16-aligned, bank-spreading pad)

typedef __bf16 bf16x8 __attribute__((ext_vector_type(8)));
typedef float  f32x4  __attribute__((ext_vector_type(4)));
typedef int    v8i    __attribute__((ext_vector_type(8)));
union U128 { uint4 u; bf16x8 v; };
union U64  { uint2 u; long l; };
union U256 { unsigned u[8]; v8i v; };

__device__ __forceinline__ unsigned f2bfu(float x) {
    unsigned u = __float_as_uint(x);
    return (u + 0x7fffu + ((u >> 16) & 1u)) >> 16;
}
__device__ __forceinline__ unsigned pk2(float lo, float hi) {
    return f2bfu(lo) | (f2bfu(hi) << 16);
}
__device__ __forceinline__ float bf2f(unsigned short h) {
    return __uint_as_float(((unsigned)h) << 16);
}
__device__ __forceinline__ unsigned pk4bf8(float a, float b, float c, float d) {
    int r = __builtin_amdgcn_cvt_pk_bf8_f32(a, b, 0, false);
    r = __builtin_amdgcn_cvt_pk_bf8_f32(c, d, r, true);
    return (unsigned)r;
}
__device__ __forceinline__ float dot8(uint4 a, const float* uq) {
    return bf2f((unsigned short)(a.x & 0xffffu)) * uq[0]
         + bf2f((unsigned short)(a.x >> 16))     * uq[1]
         + bf2f((unsigned short)(a.y & 0xffffu)) * uq[2]
         + bf2f((unsigned short)(a.y >> 16))     * uq[3]
         + bf2f((unsigned short)(a.z & 0xffffu)) * uq[4]
         + bf2f((unsigned short)(a.z >> 16))     * uq[5]
         + bf2f((unsigned short)(a.w & 0xffffu)) * uq[6]
         + bf2f((unsigned short)(a.w >> 16))     * uq[7];
}

// ===========================================================================
// Phase 1 (MX-fp8 K=128): round-17 structure, but qt8 rows padded to 272 B
// (no block rotation) -> ds_read_b128 A-loads hit the uniform 8-word/bank
// LDS floor (bank = (4*row + 8*blk + word) % 32).
// ===========================================================================
__global__ __launch_bounds__(256, 2) void crf_phase1(
        const float* __restrict__ emit, const float* __restrict__ trans,
        char* __restrict__ outX) {
    __shared__ alignas(16) char qt8[256 * QSTR];  // QT[j][k] bf8, padded rows
    __shared__ alignas(16) char scr[4][2048];     // exchange: 16 rows x 128 B/wave
    __shared__ alignas(16) float eld[2][NTS];     // exp(emit row), dbuf

    const int t    = threadIdx.x;
    const int lane = t & 63;
    const int w    = t >> 6;              // 0..3
    const int gl   = lane >> 4;           // 0..3
    const int ln15 = lane & 15;
    const int c    = blockIdx.x >> 1;
    const int h    = blockIdx.x & 1;
    const int istart = (c == 0) ? 1 : CLEN * c;
    const int iend   = CLEN * c + CLEN;

    // ---- stage QT[j][k] = exp(trans[k][j]) as bf8, natural blocks --------
    for (int gk = 0; gk < 32; gk++) {
        float v[8];
        #pragma unroll
        for (int e = 0; e < 8; e++) v[e] = __expf(trans[(gk * 8 + e) * NTS + t]);
        uint2 u;
        u.x = pk4bf8(v[0], v[1], v[2], v[3]);
        u.y = pk4bf8(v[4], v[5], v[6], v[7]);
        *(uint2*)(qt8 + t * QSTR + (gk >> 2) * 32 + (gk & 3) * 8) = u;
    }
    eld[istart & 1][t] = __expf(emit[istart * NTS + t]);

    // ---- A-read block offsets: lane needs block g4 = kf2*4 + gl ----------
    const int aoff0 = gl * 32;            // kf2 = 0
    const int aoff1 = 128 + gl * 32;      // kf2 = 1

    // ---- B := Identity columns (bf8 1.0 = 0x3C), rs := 0 -----------------
    v8i Bf[2][2];
    #pragma unroll
    for (int kf2 = 0; kf2 < 2; kf2++)
        #pragma unroll
        for (int cb = 0; cb < 2; cb++) {
            U256 b;
            #pragma unroll
            for (int q = 0; q < 8; q++) b.u[q] = 0u;
            const int r_glob = 128 * h + 32 * w + cb * 16 + ln15;
            const int e = r_glob - kf2 * 128 - gl * 32;
            if (e >= 0 && e < 32) b.u[e >> 2] = 0x3Cu << (8 * (e & 3));
            Bf[kf2][cb] = b.v;
        }
    float rs[2] = {0.f, 0.f};
    const int swz = (ln15 & 7) << 4;
    __syncthreads();

    char* const mysc = &scr[w][0];
    for (int i = istart; i < iend; ++i) {
        float enext = 0.f;
        if (i + 1 < iend) enext = emit[(i + 1) * NTS + t];

        // ---- C = QT * B (MX bf8 MFMA, K=128, unit scales) -----------------
        f32x4 Cacc[16][2];
        #pragma unroll
        for (int jb = 0; jb < 16; jb++)
            #pragma unroll
            for (int cb = 0; cb < 2; cb++) Cacc[jb][cb] = f32x4{0.f, 0.f, 0.f, 0.f};

        #pragma unroll
        for (int jb = 0; jb < 16; jb++) {
            const char* rowb = qt8 + (jb * 16 + ln15) * QSTR;
            #pragma unroll
            for (int kf2 = 0; kf2 < 2; kf2++) {
                const int ao = kf2 ? aoff1 : aoff0;
                uint4 lo = *(const uint4*)(rowb + ao);
                uint4 hi = *(const uint4*)(rowb + ao + 16);
                U256 a;
                a.u[0] = lo.x; a.u[1] = lo.y; a.u[2] = lo.z; a.u[3] = lo.w;
                a.u[4] = hi.x; a.u[5] = hi.y; a.u[6] = hi.z; a.u[7] = hi.w;
                #pragma unroll
                for (int cb = 0; cb < 2; cb++)
                    Cacc[jb][cb] = __builtin_amdgcn_mfma_scale_f32_16x16x128_f8f6f4(
                        a.v, Bf[kf2][cb], Cacc[jb][cb],
                        1, 1,            // cbsz=bf8(e5m2), blgp=bf8(e5m2)
                        0, 0x7F,         // opsel_a, scale_a (e8m0 127 = x1)
                        0, 0x7F);        // opsel_b, scale_b
            }
        }

        // ---- scale rows j by exp(emit[i][j]) ------------------------------
        #pragma unroll
        for (int jb = 0; jb < 16; jb++) {
            float4 ev = *(const float4*)&eld[i & 1][jb * 16 + gl * 4];
            #pragma unroll
            for (int cb = 0; cb < 2; cb++) {
                Cacc[jb][cb][0] *= ev.x; Cacc[jb][cb][1] *= ev.y;
                Cacc[jb][cb][2] *= ev.z; Cacc[jb][cb][3] *= ev.w;
            }
        }
        // ---- per-column max + renormalize ---------------------------------
        float rn[2];
        #pragma unroll
        for (int cb = 0; cb < 2; cb++) {
            float m0 = Cacc[0][cb][0];
            #pragma unroll
            for (int jb = 0; jb < 16; jb++)
                #pragma unroll
                for (int rg = 0; rg < 4; rg++) m0 = fmaxf(m0, Cacc[jb][cb][rg]);
            m0 = fmaxf(m0, __shfl_xor(m0, 16));
            m0 = fmaxf(m0, __shfl_xor(m0, 32));
            rn[cb] = 1.0f / m0;
            rs[cb] += __logf(m0);
        }

        if (i == iend - 1) {
            // ---- coalesced write: scatter into qt8 (dead), then copy out ---
            __syncthreads();              // all waves done reading qt8 (MFMA)
            #pragma unroll
            for (int jb = 0; jb < 16; jb++)
                #pragma unroll
                for (int cb = 0; cb < 2; cb++) {
                    int rsl = w * 32 + cb * 16 + ln15;
                    #pragma unroll
                    for (int rg = 0; rg < 4; rg++) {
                        int j = jb * 16 + gl * 4 + rg;
                        *(unsigned short*)(qt8 + ((j * 128 + rsl) << 1)) =
                            (unsigned short)f2bfu(Cacc[jb][cb][rg] * rn[cb]);
                    }
                }
            __syncthreads();
            char* SO = outX + (size_t)(2 * c + h) * SLOT2;
            #pragma unroll
            for (int q = 0; q < 16; q++)
                *(uint4*)(SO + q * 4096 + t * 16) =
                    *(const uint4*)(qt8 + q * 4096 + t * 16);
            if (lane < 16) {
                #pragma unroll
                for (int cb = 0; cb < 2; cb++) {
                    int rsl = w * 32 + cb * 16 + lane;
                    *(float*)(SO + 65536 + rsl * 4) = rs[cb];
                }
            }
        } else {
            // ---- C -> next B (bf8) via 4-round intra-wave exchange ---------
            #pragma unroll
            for (int kf2 = 0; kf2 < 2; kf2++) {
                #pragma unroll
                for (int cb = 0; cb < 2; cb++) {
                    #pragma unroll
                    for (int jbl = 0; jbl < 8; jbl++) {
                        const int jb = kf2 * 8 + jbl;
                        unsigned pk = pk4bf8(Cacc[jb][cb][0] * rn[cb],
                                             Cacc[jb][cb][1] * rn[cb],
                                             Cacc[jb][cb][2] * rn[cb],
                                             Cacc[jb][cb][3] * rn[cb]);
                        const int addr = ln15 * 128 + (((jbl * 16) ^ swz) + gl * 4);
                        *(unsigned*)(mysc + addr) = pk;
                    }
                    asm volatile("s_waitcnt lgkmcnt(0)" ::: "memory");
                    __builtin_amdgcn_sched_barrier(0);
                    uint4 r0 = *(const uint4*)(mysc + ln15 * 128 + ((gl * 32) ^ swz));
                    uint4 r1 = *(const uint4*)(mysc + ln15 * 128 + ((gl * 32 + 16) ^ swz));
                    U256 b;
                    b.u[0] = r0.x; b.u[1] = r0.y; b.u[2] = r0.z; b.u[3] = r0.w;
                    b.u[4] = r1.x; b.u[5] = r1.y; b.u[6] = r1.z; b.u[7] = r1.w;
                    Bf[kf2][cb] = b.v;
                    asm volatile("s_waitcnt lgkmcnt(0)" ::: "memory");
                    __builtin_amdgcn_sched_barrier(0);
                }
            }
            eld[(i + 1) & 1][t] = __expf(enext);
            __syncthreads();
        }
    }
}

// ===========================================================================
// Binary-combine body (round-9, proven): out (p,h) = Later(2p+1) x
// Earlier(2p), columns [128h,128h+128), linear storage.
// ===========================================================================
__device__ __forceinline__ void combine_body(
        const char* __restrict__ inb, char* __restrict__ outb,
        int p, int h, char* qt, unsigned (*scr)[512],
        float* efac, float* smax,
        int t, int lane, int w, int gl, int ln15) {
    const char* SL0 = inb + (size_t)(4 * p + 2) * SLOT2;
    const char* SL1 = inb + (size_t)(4 * p + 3) * SLOT2;
    const char* SE  = inb + (size_t)(4 * p + h) * SLOT2;
    char* SO = outb + (size_t)(2 * p + h) * SLOT2;

    float sv = *(const float*)(((t < 128) ? SL0 : SL1) + 65536 + (t & 127) * 4);
    float m = sv;
    #pragma unroll
    for (int off = 32; off; off >>= 1) m = fmaxf(m, __shfl_xor(m, off));
    if (lane == 0) smax[w] = m;
    __syncthreads();
    const float sigma = fmaxf(fmaxf(smax[0], smax[1]), fmaxf(smax[2], smax[3]));
    efac[t] = __expf(sv - sigma);
    __syncthreads();

    for (int it = 0; it < 32; it++) {
        int off = it * 2048 + t * 8;
        int j = off >> 8, k = off & 255;
        const char* src = (k < 128) ? (SL0 + (size_t)(j * 128 + k) * 2)
                                    : (SL1 + (size_t)(j * 128 + (k - 128)) * 2);
        uint4 d = *(const uint4*)src;
        float4 e0 = *(const float4*)&efac[k];
        float4 e1 = *(const float4*)&efac[k + 4];
        float ef[8] = {e0.x, e0.y, e0.z, e0.w, e1.x, e1.y, e1.z, e1.w};
        unsigned wds[4] = {d.x, d.y, d.z, d.w};
        unsigned outw[4];
        #pragma unroll
        for (int wi = 0; wi < 4; wi++) {
            float lo = bf2f((unsigned short)(wds[wi] & 0xffffu)) * ef[2 * wi];
            float hi = bf2f((unsigned short)(wds[wi] >> 16)) * ef[2 * wi + 1];
            outw[wi] = pk2(lo, hi);
        }
        uint4 o; o.x = outw[0]; o.y = outw[1]; o.z = outw[2]; o.w = outw[3];
        *(uint4*)(qt + ((j * 512 + k * 2) ^ ((j & 7) << 4))) = o;
    }

    bf16x8 Bf[8][2];
    #pragma unroll
    for (int kf = 0; kf < 8; kf++) {
        #pragma unroll
        for (int p2 = 0; p2 < 2; p2++) {
            int kk = p2 * 16 + (lane >> 2);
            uint4 d = *(const uint4*)(SE + (size_t)(32 * kf + kk) * 256
                                      + w * 64 + (lane & 3) * 16);
            *(uint4*)((char*)&scr[w][0] + kk * 64 + (lane & 3) * 16) = d;
        }
        asm volatile("s_waitcnt lgkmcnt(0)" ::: "memory");
        __builtin_amdgcn_sched_barrier(0);
        #pragma unroll
        for (int cb = 0; cb < 2; cb++) {
            unsigned wd[4] = {0u, 0u, 0u, 0u};
            #pragma unroll
            for (int e = 0; e < 8; e++) {
                int kloc = gl * 8 + e;
                unsigned short hh = *(const unsigned short*)
                    ((const char*)&scr[w][0] + kloc * 64 + (cb * 16 + ln15) * 2);
                wd[e >> 1] |= ((unsigned)hh) << (16 * (e & 1));
            }
            U128 q; q.u.x = wd[0]; q.u.y = wd[1]; q.u.z = wd[2]; q.u.w = wd[3];
            Bf[kf][cb] = q.v;
        }
        asm volatile("s_waitcnt lgkmcnt(0)" ::: "memory");
        __builtin_amdgcn_sched_barrier(0);
    }
    __syncthreads();

    f32x4 Cacc[16][2];
    #pragma unroll
    for (int jb = 0; jb < 16; jb++)
        #pragma unroll
        for (int cb = 0; cb < 2; cb++) Cacc[jb][cb] = f32x4{0.f, 0.f, 0.f, 0.f};
    const int aswz = (lane & 7) << 4;
    #pragma unroll
    for (int jb = 0; jb < 16; jb++) {
        const int abase = (jb * 16 + ln15) * 512 + gl * 16;
        #pragma unroll
        for (int kf = 0; kf < 8; kf++) {
            U128 a; a.u = *(const uint4*)(qt + ((abase + kf * 64) ^ aswz));
            #pragma unroll
            for (int cb = 0; cb < 2; cb++)
                Cacc[jb][cb] = __builtin_amdgcn_mfma_f32_16x16x32_bf16(
                    a.v, Bf[kf][cb], Cacc[jb][cb], 0, 0, 0);
        }
    }

    float mx[2], rn[2];
    #pragma unroll
    for (int cb = 0; cb < 2; cb++) {
        float m0 = Cacc[0][cb][0];
        #pragma unroll
        for (int jb = 0; jb < 16; jb++)
            #pragma unroll
            for (int rg = 0; rg < 4; rg++) m0 = fmaxf(m0, Cacc[jb][cb][rg]);
        m0 = fmaxf(m0, __shfl_xor(m0, 16));
        m0 = fmaxf(m0, __shfl_xor(m0, 32));
        mx[cb] = m0; rn[cb] = 1.0f / m0;
    }

    __syncthreads();
    #pragma unroll
    for (int jb = 0; jb < 16; jb++)
        #pragma unroll
        for (int cb = 0; cb < 2; cb++) {
            int rsl = w * 32 + cb * 16 + ln15;
            #pragma unroll
            for (int rg = 0; rg < 4; rg++) {
                int j = jb * 16 + gl * 4 + rg;
                *(unsigned short*)(qt + ((j * 128 + rsl) << 1)) =
                    (unsigned short)f2bfu(Cacc[jb][cb][rg] * rn[cb]);
            }
        }
    __syncthreads();
    #pragma unroll
    for (int q = 0; q < 16; q++)
        *(uint4*)(SO + q * 4096 + t * 16) = *(const uint4*)(qt + q * 4096 + t * 16);
    if (lane < 16) {
        #pragma unroll
        for (int cb = 0; cb < 2; cb++) {
            int rsl = w * 32 + cb * 16 + lane;
            float se = *(const float*)(SE + 65536 + rsl * 4);
            *(float*)(SO + 65536 + rsl * 4) = se + sigma + __logf(mx[cb]);
        }
    }
}

__global__ __launch_bounds__(256, 1) void crf_combine2(
        const char* __restrict__ inb, char* __restrict__ outb) {
    __shared__ alignas(16) char qt[131072];
    __shared__ alignas(16) unsigned scr[4][512];
    __shared__ alignas(16) float efac[NTS];
    __shared__ float smax[4];
    const int t = threadIdx.x;
    combine_body(inb, outb, blockIdx.x >> 1, blockIdx.x & 1, qt, scr, efac, smax,
                 t, t & 63, t >> 6, (t & 63) >> 4, t & 15);
}

// ===========================================================================
// Fused chain + finalize + gold (round-9/15, proven): 16 serial matvecs.
// ===========================================================================
__global__ __launch_bounds__(512) void crf_chainfin16(
        const char* __restrict__ mats, const float* __restrict__ emit,
        const float* __restrict__ BOS, const int* __restrict__ y,
        const float* __restrict__ trans, const float* __restrict__ EOS,
        float* __restrict__ out) {
    __shared__ float red[8];
    __shared__ float smx[8];
    __shared__ alignas(16) float u[NTS];
    __shared__ float pu[NTS];
    const int t = threadIdx.x, lane = t & 63, wv = t >> 6;

    float s = 0.f;
    for (int i = t; i < TLEN - 1; i += 512) {
        int yi = y[i], yn = y[i + 1];
        s += trans[yi * NTS + yn] + emit[i * NTS + yi];
    }
    #pragma unroll
    for (int off = 32; off; off >>= 1) s += __shfl_down(s, off);
    if (lane == 0) red[wv] = s;

    float v0 = (t < NTS) ? (BOS[t] + emit[t]) : -INFINITY;
    float m = v0;
    #pragma unroll
    for (int off = 32; off; off >>= 1) m = fmaxf(m, __shfl_xor(m, off));
    if (lane == 0) smx[wv] = m;
    __syncthreads();
    const float m0 = fmaxf(fmaxf(smx[0], smx[1]), fmaxf(smx[2], smx[3]));
    float wreg = (t < NTS) ? __expf(v0 - m0) : 0.f;
    double W = (double)m0;
    __syncthreads();

    const int j2 = t & 255;
    const int hh = t >> 8;
    for (int c = 0; c < 16; ++c) {
        const char* M0 = mats + (size_t)(2 * c) * SLOT2;
        const char* M1 = M0 + SLOT2;

        const char* Mh = hh ? M1 : M0;
        const uint4* rowp = (const uint4*)(Mh + (size_t)j2 * 256);
        uint4 regs[16];
        #pragma unroll
        for (int q = 0; q < 16; q++) regs[q] = rowp[q];

        float sv = -INFINITY;
        if (t < NTS) sv = *(const float*)(((t < 128) ? M0 : M1) + 65536 + (t & 127) * 4);
        m = sv;
        #pragma unroll
        for (int off = 32; off; off >>= 1) m = fmaxf(m, __shfl_xor(m, off));
        if (lane == 0) smx[wv] = m;
        __syncthreads();
        const float sigma = fmaxf(fmaxf(smx[0], smx[1]), fmaxf(smx[2], smx[3]));
        if (t < NTS) u[t] = __expf(sv - sigma) * wreg;
        __syncthreads();

        const float* ub = u + hh * 128;
        float acc = 0.f;
        #pragma unroll
        for (int q = 0; q < 16; q++) acc += dot8(regs[q], ub + q * 8);
        if (hh == 1) pu[j2] = acc;
        __syncthreads();
        float v = -INFINITY;
        if (t < NTS) v = acc + pu[t];
        m = v;
        #pragma unroll
        for (int off = 32; off; off >>= 1) m = fmaxf(m, __shfl_xor(m, off));
        if (lane == 0) smx[wv] = m;
        __syncthreads();
        const float mstep = fmaxf(fmaxf(smx[0], smx[1]), fmaxf(smx[2], smx[3]));
        W += (double)(sigma + __logf(mstep));
        if (t < NTS) wreg = v * (1.0f / mstep);
        __syncthreads();
    }

    float ssum = (t < NTS) ? wreg : 0.f;
    #pragma unroll
    for (int off = 32; off; off >>= 1) ssum += __shfl_down(ssum, off);
    if (lane == 0) smx[wv] = ssum;
    __syncthreads();
    if (t == 0) {
        float S = smx[0] + smx[1] + smx[2] + smx[3];
        float logZ = (float)(W + (double)__logf(S));
        float gold = 0.f;
        #pragma unroll
        for (int k = 0; k < 8; k++) gold += red[k];
        int y0 = y[0], yl = y[TLEN - 1];
        gold += BOS[y0] + EOS[yl] + emit[(TLEN - 1) * NTS + yl];
        out[0] = logZ - gold;
    }
}

// ===========================================================================
// Serial fallback (ws too small) — unchanged, verified
// ===========================================================================
__global__ __launch_bounds__(256) void crf_prep(const float* __restrict__ trans,
                                                __half2* __restrict__ Qp) {
    int j = threadIdx.x, p = blockIdx.x;
    float a = __expf(trans[(2 * p) * NTS + j]);
    float b = __expf(trans[(2 * p + 1) * NTS + j]);
    Qp[p * NTS + j] = __floats2half2_rn(a, b);
}

__global__ __launch_bounds__(512) void crf_forward(
        const float* __restrict__ emit, const float* __restrict__ BOS,
        const __half2* __restrict__ Qp_g, float* __restrict__ logZ_out) {
    __shared__ __half2 Qp[128 * NTS];
    __shared__ alignas(16) float w[NTS];
    __shared__ float part[2][NTS];
    __shared__ float ebuf[2][NTS];
    __shared__ float wavemax[8];
    const int t = threadIdx.x, j = t & 255, q = t >> 8, lane = t & 63, wv = t >> 6;
    for (int idx = t; idx < 128 * NTS; idx += 512) Qp[idx] = Qp_g[idx];
    float anew = -INFINITY;
    if (t < NTS) anew = BOS[t] + emit[t];
    float ml = anew;
    #pragma unroll
    for (int off = 32; off; off >>= 1) ml = fmaxf(ml, __shfl_down(ml, off));
    if (lane == 0) wavemax[wv] = ml;
    __syncthreads();
    float mstep = fmaxf(fmaxf(wavemax[0], wavemax[1]), fmaxf(wavemax[2], wavemax[3]));
    double Macc = (double)mstep;
    if (t < NTS) w[t] = __expf(anew - mstep);
    float epre = 0.f;
    if (q == 1) epre = emit[NTS + j];
    __syncthreads();
    for (int i = 1; i < TLEN; ++i) {
        if (q == 1) ebuf[i & 1][j] = epre;
        float acc = 0.f;
        const __half2* qptr = Qp + (q * 64) * NTS + j;
        const float2* wptr = (const float2*)(w + q * 128);
        #pragma unroll 16
        for (int kk = 0; kk < 64; ++kk) {
            __half2 qv = qptr[kk * NTS];
            float2 wv2 = wptr[kk];
            acc += __low2float(qv) * wv2.x + __high2float(qv) * wv2.y;
        }
        part[q][j] = acc;
        if (q == 1 && (i + 1) < TLEN) epre = emit[(i + 1) * NTS + j];
        __syncthreads();
        float an = 0.f;
        ml = -INFINITY;
        if (t < NTS) {
            float vv = part[0][t] + part[1][t];
            an = ebuf[i & 1][t] + __logf(vv);
            ml = an;
        }
        #pragma unroll
        for (int off = 32; off; off >>= 1) ml = fmaxf(ml, __shfl_down(ml, off));
        if (lane == 0 && wv < 4) wavemax[wv] = ml;
        __syncthreads();
        mstep = fmaxf(fmaxf(wavemax[0], wavemax[1]), fmaxf(wavemax[2], wavemax[3]));
        Macc += (double)mstep;
        if (t < NTS) w[t] = __expf(an - mstep);
        __syncthreads();
    }
    float s = (t < NTS) ? w[t] : 0.f;
    #pragma unroll
    for (int off = 32; off; off >>= 1) s += __shfl_down(s, off);
    if (lane == 0 && wv < 4) wavemax[wv] = s;
    __syncthreads();
    if (t == 0) {
        float tot = wavemax[0] + wavemax[1] + wavemax[2] + wavemax[3];
        logZ_out[0] = (float)(Macc + (double)__logf(tot));
    }
}

__global__ __launch_bounds__(512) void crf_gold(
        const float* __restrict__ emit, const int* __restrict__ y,
        const float* __restrict__ trans, const float* __restrict__ BOS,
        const float* __restrict__ EOS, const float* __restrict__ logZ_ws,
        float* __restrict__ out) {
    __shared__ float red[8];
    int t = threadIdx.x;
    float s = 0.f;
    for (int i = t; i < TLEN - 1; i += 512) {
        int yi = y[i], yn = y[i + 1];
        s += trans[yi * NTS + yn] + emit[i * NTS + yi];
    }
    #pragma unroll
    for (int off = 32; off; off >>= 1) s += __shfl_down(s, off);
    if ((t & 63) == 0) red[t >> 6] = s;
    __syncthreads();
    if (t == 0) {
        float tot = 0.f;
        #pragma unroll
        for (int k2 = 0; k2 < 8; ++k2) tot += red[k2];
        int y0 = y[0], yl = y[TLEN - 1];
        tot += BOS[y0] + EOS[yl] + emit[(TLEN - 1) * NTS + yl];
        out[0] = logZ_ws[0] - tot;
    }
}

// ===========================================================================
extern "C" void kernel_launch(void* const* d_in, const int* in_sizes, int n_in,
                              void* d_out, int out_size, void* d_ws, size_t ws_size,
                              hipStream_t stream) {
    const float* emit  = (const float*)d_in[0];
    const int*   y     = (const int*)d_in[1];
    const float* trans = (const float*)d_in[2];
    const float* BOS   = (const float*)d_in[3];
    const float* EOS   = (const float*)d_in[4];
    float* out = (float*)d_out;

    const size_t need = (size_t)(512 + 256) * SLOT2 + 256;
    if (ws_size >= need) {
        char* X = (char*)d_ws;                       // 512 half-slots
        char* Y = X + (size_t)512 * SLOT2;           // 256 half-slots

        crf_phase1<<<2 * NCH, 256, 0, stream>>>(emit, trans, X);
        crf_combine2<<<256, 256, 0, stream>>>(X, Y);   // 256 -> 128 matrices
        crf_combine2<<<128, 256, 0, stream>>>(Y, X);   // 128 -> 64
        crf_combine2<<<64, 256, 0, stream>>>(X, Y);    //  64 -> 32
        crf_combine2<<<32, 256, 0, stream>>>(Y, X);    //  32 -> 16
        crf_chainfin16<<<1, 512, 0, stream>>>(X, emit, BOS, y, trans, EOS, out);
    } else {
        __half2* Qp = (__half2*)d_ws;
        float* logZ = (float*)((char*)d_ws + 128 * NTS * sizeof(__half2));
        crf_prep<<<128, 256, 0, stream>>>(trans, Qp);
        crf_forward<<<1, 512, 0, stream>>>(emit, BOS, Qp, logZ);
        crf_gold<<<1, 512, 0, stream>>>(emit, y, trans, BOS, EOS, logZ, out);
    }
}